// Round 5
// baseline (1798.948 us; speedup 1.0000x reference)
//
#include <hip/hip_runtime.h>

typedef __attribute__((ext_vector_type(8))) short short8;
typedef __attribute__((ext_vector_type(4))) float floatx4;

#define D_   1024
#define L_   4096
#define B_   4
#define T_   16384
#define NCH  32     // scan chunks per sequence
#define CHL  128    // scan chunk length

__device__ __forceinline__ ushort f2bf(float f) {
  unsigned u = __float_as_uint(f);
  u += 0x7fffu + ((u >> 16) & 1u);   // round-to-nearest-even
  return (ushort)(u >> 16);
}
__device__ __forceinline__ float bf2f(ushort u) {
  return __uint_as_float(((unsigned)u) << 16);
}

// async global->LDS, 16B per lane. LDS dest MUST be wave-uniform base + lane*16.
__device__ __forceinline__ void gl2lds(const ushort* g, ushort* l) {
  __builtin_amdgcn_global_load_lds(
      (const __attribute__((address_space(1))) unsigned int*)g,
      (__attribute__((address_space(3))) unsigned int*)l, 16, 0, 0);
}

// ---------------- weight fp32 -> bf16 ----------------
__global__ __launch_bounds__(256) void cvt_bf(const float* __restrict__ s,
                                              ushort* __restrict__ d, int n4) {
  int i = blockIdx.x * 256 + threadIdx.x;
  if (i >= n4) return;
  float4 v = ((const float4*)s)[i];
  ushort4 o;
  o.x = f2bf(v.x); o.y = f2bf(v.y); o.z = f2bf(v.z); o.w = f2bf(v.w);
  ((ushort4*)d)[i] = o;
}

// ---------------- fused rmsnorm + gamma-scale -> bf16 (stages 2,3) ----------------
__global__ __launch_bounds__(256) void rms_scale(const float* __restrict__ x,
                                                 const float* __restrict__ g,
                                                 ushort* __restrict__ z) {
  int t = blockIdx.x;
  float4 v = ((const float4*)(x + (size_t)t * D_))[threadIdx.x];
  float s = v.x * v.x + v.y * v.y + v.z * v.z + v.w * v.w;
#pragma unroll
  for (int off = 32; off > 0; off >>= 1) s += __shfl_xor(s, off, 64);
  __shared__ float red[4];
  if ((threadIdx.x & 63) == 0) red[threadIdx.x >> 6] = s;
  __syncthreads();
  float iv = 32.0f / fmaxf(sqrtf(red[0] + red[1] + red[2] + red[3]), 1e-12f);
  float4 gg = ((const float4*)g)[threadIdx.x];
  ushort4 o;
  o.x = f2bf(v.x * iv * (gg.x + 1.f));
  o.y = f2bf(v.y * iv * (gg.y + 1.f));
  o.z = f2bf(v.z * iv * (gg.z + 1.f));
  o.w = f2bf(v.w * iv * (gg.w + 1.f));
  ((ushort4*)(z + (size_t)t * D_))[threadIdx.x] = o;
}

// ---------------- fused rmsnorm (3 norms in-block) + causal dwconv (K=3) ----------------
__global__ __launch_bounds__(256) void dwconv_k(const float* __restrict__ x,
                                                const float* __restrict__ wdw,
                                                const float* __restrict__ bdw,
                                                const float* __restrict__ gm,
                                                ushort* __restrict__ y) {
  int t = blockIdx.x;
  int c4 = threadIdx.x << 2;
  int l = t & (L_ - 1);
  const float* p0 = x + (size_t)t * D_ + c4;
  float4 v0 = *(const float4*)p0;
  float4 v1 = {0.f, 0.f, 0.f, 0.f}, v2 = {0.f, 0.f, 0.f, 0.f};
  if (l >= 1) v1 = *(const float4*)(p0 - D_);
  if (l >= 2) v2 = *(const float4*)(p0 - 2 * D_);
  float s0 = v0.x * v0.x + v0.y * v0.y + v0.z * v0.z + v0.w * v0.w;
  float s1 = v1.x * v1.x + v1.y * v1.y + v1.z * v1.z + v1.w * v1.w;
  float s2 = v2.x * v2.x + v2.y * v2.y + v2.z * v2.z + v2.w * v2.w;
#pragma unroll
  for (int off = 32; off > 0; off >>= 1) {
    s0 += __shfl_xor(s0, off, 64);
    s1 += __shfl_xor(s1, off, 64);
    s2 += __shfl_xor(s2, off, 64);
  }
  __shared__ float r0[4], r1[4], r2[4];
  if ((threadIdx.x & 63) == 0) {
    int w = threadIdx.x >> 6;
    r0[w] = s0; r1[w] = s1; r2[w] = s2;
  }
  __syncthreads();
  float i0 = 32.0f / fmaxf(sqrtf(r0[0] + r0[1] + r0[2] + r0[3]), 1e-12f);
  float i1 = 32.0f / fmaxf(sqrtf(r1[0] + r1[1] + r1[2] + r1[3]), 1e-12f);
  float i2 = 32.0f / fmaxf(sqrtf(r2[0] + r2[1] + r2[2] + r2[3]), 1e-12f);
  float a0[4] = {v0.x, v0.y, v0.z, v0.w};
  float a1[4] = {v1.x, v1.y, v1.z, v1.w};
  float a2[4] = {v2.x, v2.y, v2.z, v2.w};
  ushort r[4];
#pragma unroll
  for (int j = 0; j < 4; ++j) {
    int d = c4 + j;
    float w0 = wdw[d * 3 + 0], w1 = wdw[d * 3 + 1], w2 = wdw[d * 3 + 2];
    float s = w2 * a0[j] * i0 + w1 * a1[j] * i1 + w0 * a2[j] * i2;
    s = s * (gm[d] + 1.0f) + bdw[d];
    r[j] = f2bf(s);
  }
  ushort4 o; o.x = r[0]; o.y = r[1]; o.z = r[2]; o.w = r[3];
  *(ushort4*)(y + (size_t)t * D_ + c4) = o;
}

// ---------------- 256x256 8-phase bf16 MFMA GEMM (register-pipelined) ----------------
// A: [M][K] bf16 row-major, W: [N][K] bf16 row-major. C = A @ W^T.
// 512 threads = 8 waves (2M x 4N); per-wave 128x64 output; BK=64; 128 KiB LDS dbuf.
// r5 mechanism: one 16-MFMA QUADRANT per phase; each phase's ds_reads target the
// operand set of a LATER cluster, held in distinct arrays (aE0/aE1/bE0/bE1 and
// odd-tile mirrors). No phase re-reads into registers still consumed by the
// in-flight MFMA cluster -> no WAR stall -> LDS service pipelines under MFMA.
// Peak fragment liveness ~96 VGPR, fits the 128-arch budget (acc = 128 AGPR).
// LDS swizzle: k-slot s holds global slot s ^ (row&7) (pre-swizzled global src,
// linear global_load_lds dest; matching XOR on ds_read side -> 0 bank conflicts).
// vmcnt ledger (per 2-tile iter, enter 4 outstanding {B(m+1)}):
//  P1 +2(A m+1 h0)=6  P2 +2(h1)=8  P3 +4(B m+2)=12 -> vmcnt(4): lands B(m+1),A(m+1)
//  P5 +2(A m+2 h0)=6  P6 +2(h1)=8  P7 +4(B m+3)=12 -> vmcnt(4): lands B(m+2),A(m+2)
// MODE 0: outF = acc + bias + resid. MODE 2: outB = bf16(gelu(acc+bias)).
// MODE 4: minGRU gates: col<1024 -> g(acc); col>=1024 -> sigmoid(-acc).

#define DS_A(DST, PB, MQ)                                                    \
  _Pragma("unroll") for (int mf_ = 0; mf_ < 4; ++mf_) {                      \
    DST[2 * mf_]     = *(const short8*)((PB) + (MQ) + mf_ * 1024 + o0);      \
    DST[2 * mf_ + 1] = *(const short8*)((PB) + (MQ) + mf_ * 1024 + o1);      \
  }

#define DS_B(DST, PB, NH)                                                    \
  _Pragma("unroll") for (int nf_ = 0; nf_ < 2; ++nf_) {                      \
    DST[2 * nf_]     = *(const short8*)((PB) + (NH) * 2048 + nf_ * 1024 + o0); \
    DST[2 * nf_ + 1] = *(const short8*)((PB) + (NH) * 2048 + nf_ * 1024 + o1); \
  }

#define MFMA_C(AS, BS, MB, NB)                                               \
  __builtin_amdgcn_s_setprio(1);                                             \
  _Pragma("unroll") for (int mf_ = 0; mf_ < 4; ++mf_) {                      \
    _Pragma("unroll") for (int nf_ = 0; nf_ < 2; ++nf_) {                    \
      floatx4 c_ = acc[(MB) + mf_][(NB) + nf_];                              \
      c_ = __builtin_amdgcn_mfma_f32_16x16x32_bf16(AS[2 * mf_],              \
             BS[2 * nf_], c_, 0, 0, 0);                                      \
      c_ = __builtin_amdgcn_mfma_f32_16x16x32_bf16(AS[2 * mf_ + 1],          \
             BS[2 * nf_ + 1], c_, 0, 0, 0);                                  \
      acc[(MB) + mf_][(NB) + nf_] = c_;                                      \
    }                                                                        \
  }                                                                          \
  __builtin_amdgcn_s_setprio(0)

#define BAR_LGKM()                                    \
  asm volatile("s_barrier" ::: "memory");             \
  asm volatile("s_waitcnt lgkmcnt(0)" ::: "memory");  \
  __builtin_amdgcn_sched_barrier(0)

#define BAR_END()                          \
  asm volatile("s_barrier" ::: "memory");  \
  __builtin_amdgcn_sched_barrier(0)

template <int MODE>
__global__ __launch_bounds__(512, 2) void gemm256(
    const ushort* __restrict__ A, const ushort* __restrict__ W,
    const float* __restrict__ bias, const float* __restrict__ resid,
    float* __restrict__ outF, ushort* __restrict__ outB, int M, int N, int K) {
  __shared__ ushort lds[65536];  // 128 KiB: buf{0,1} x (A[256][64] | B[256][64])
  const int tid = threadIdx.x;

  // --- XCD-aware bijective remap (gridDim.y == 64, nx power of 2 -> nwg%8==0) ---
  const int nx = gridDim.x;
  const int lxs = 31 - __clz(nx);
  const int lin = blockIdx.x + blockIdx.y * nx;
  const int cpx = nx << 3;                 // nwg/8 = nx*64/8
  const int wg = (lin & 7) * cpx + (lin >> 3);
  const int bm = (wg >> lxs) << 8;
  const int bn = (wg & (nx - 1)) << 8;

  const int lane = tid & 63, wave = tid >> 6;
  const int wm = (wave >> 2) & 1;          // M half of the tile
  const int wn = wave & 3;                 // N quarter
  const int fr = lane & 15, fq = lane >> 4;

  // staging: thread t -> row srow (64 rows/round), swizzled k-slot source
  const int srow = tid >> 3;               // 0..63
  const int kcs = (tid & 7) ^ (srow & 7);  // pre-swizzled global k-slot
  const ushort* gA = A + (size_t)(bm + srow) * K + kcs * 8;
  const ushort* gB = W + (size_t)(bn + srow) * K + kcs * 8;
  ushort* ldst = lds + tid * 8;            // linear LDS dest (lane*16B)

  // read-side bases (swizzled slot = j ^ (fr&7), j = ks*4 + fq)
  const ushort* pA0 = lds + (size_t)(wm * 128 + fr) * 64;
  const ushort* pB0 = lds + 16384 + (size_t)(wn * 64 + fr) * 64;
  const ushort* pA1 = pA0 + 32768;
  const ushort* pB1 = pB0 + 32768;
  const int o0 = (fq ^ (fr & 7)) * 8;
  const int o1 = o0 ^ 32;

  floatx4 acc[8][4];
#pragma unroll
  for (int i = 0; i < 8; ++i)
#pragma unroll
    for (int j = 0; j < 4; ++j) acc[i][j] = {0.f, 0.f, 0.f, 0.f};
  // fragment sets: E = even tile (buf0), O = odd tile (buf1)
  short8 aE0[8], aE1[8], aO0[8], aO1[8];
  short8 bE0[4], bE1[4], bO0[4], bO1[4];

  auto stageA = [&](int buf, int half, int kt) {
    const ushort* s = gA + (size_t)(half * 128) * K + kt * 64;
    ushort* d = ldst + buf * 32768 + half * 8192;
    gl2lds(s, d);
    gl2lds(s + (size_t)64 * K, d + 4096);
  };
  auto stageB = [&](int buf, int half, int kt) {
    const ushort* s = gB + (size_t)(half * 128) * K + kt * 64;
    ushort* d = ldst + buf * 32768 + 16384 + half * 8192;
    gl2lds(s, d);
    gl2lds(s + (size_t)64 * K, d + 4096);
  };

  const int nt = K >> 6;  // K-tiles of 64 (even: 16 or 64 here)

  // prologue: tile0 {A,B}, tile1 {B}; land tile0 (4 = tile1.B stay in flight)
  stageA(0, 0, 0); stageA(0, 1, 0);
  stageB(0, 0, 0); stageB(0, 1, 0);
  stageB(1, 0, 1); stageB(1, 1, 1);
  asm volatile("s_waitcnt vmcnt(4)" ::: "memory");
  BAR_END();
  DS_A(aE0, pA0, 0);                   // tile0 A quad-lo (drained by P1's lgkm)

  for (int m = 0; m < nt; m += 2) {
    const bool more = (m + 2 < nt);
    // ====== tile m (buf0): quadrants Q00 Q01 Q11 Q10 ======
    // P1
    DS_B(bE0, pB0, 0); DS_B(bE1, pB0, 1);
    stageA(1, 0, m + 1);
    BAR_LGKM();
    MFMA_C(aE0, bE0, 0, 0);
    BAR_END();
    // P2
    DS_A(aE1, pA0, 4096);
    stageA(1, 1, m + 1);
    BAR_LGKM();
    MFMA_C(aE0, bE1, 0, 2);
    BAR_END();
    // P3 (no ds_reads: pure MFMA under stage+vmcnt)
    if (more) {
      stageB(0, 0, m + 2); stageB(0, 1, m + 2);
      asm volatile("s_waitcnt vmcnt(4)" ::: "memory");  // lands B(m+1), A(m+1)
    } else {
      asm volatile("s_waitcnt vmcnt(0)" ::: "memory");
    }
    BAR_LGKM();
    MFMA_C(aE1, bE1, 4, 2);
    BAR_END();
    // P4 (buf1 valid after P3's vmcnt + barrier)
    DS_A(aO0, pA1, 0);
    BAR_LGKM();
    MFMA_C(aE1, bE0, 4, 0);
    BAR_END();

    // ====== tile m+1 (buf1) ======
    // P5
    DS_B(bO0, pB1, 0); DS_B(bO1, pB1, 1);
    if (more) stageA(0, 0, m + 2);     // buf0.A free (aE0/aE1 drained P1/P2)
    BAR_LGKM();
    MFMA_C(aO0, bO0, 0, 0);
    BAR_END();
    // P6
    DS_A(aO1, pA1, 4096);
    if (more) stageA(0, 1, m + 2);
    BAR_LGKM();
    MFMA_C(aO0, bO1, 0, 2);
    BAR_END();
    // P7
    if (more) {
      stageB(1, 0, m + 3); stageB(1, 1, m + 3);  // buf1.B free (bO* drained P5)
      asm volatile("s_waitcnt vmcnt(4)" ::: "memory");  // lands B(m+2), A(m+2)
    } else {
      asm volatile("s_waitcnt vmcnt(0)" ::: "memory");
    }
    BAR_LGKM();
    MFMA_C(aO1, bO1, 4, 2);
    BAR_END();
    // P8 (prefetch next even tile's A quad-lo from buf0)
    if (more) { DS_A(aE0, pA0, 0); }
    BAR_LGKM();
    MFMA_C(aO1, bO0, 4, 0);
    BAR_END();
  }

  // ---------------- epilogue ----------------
  const int rowb = bm + wm * 128 + fq * 4;
  const int colb = bn + wn * 64 + fr;
#pragma unroll
  for (int nf = 0; nf < 4; ++nf) {
    const int colg = colb + nf * 16;
    const float bvs = (MODE == 4) ? 0.f : bias[colg];
#pragma unroll
    for (int mf = 0; mf < 8; ++mf) {
#pragma unroll
      for (int r = 0; r < 4; ++r) {
        const int rowg = rowb + mf * 16 + r;
        const size_t idx = (size_t)rowg * N + colg;
        float v = acc[mf][nf][r];
        if (MODE == 0) {
          outF[idx] = v + bvs + resid[idx];
        } else if (MODE == 2) {
          v += bvs;
          // gelu(x) ~= x * sigmoid(1.5957691(x + 0.044715 x^3)); maxerr ~1e-3
          float u = 1.5957691216f * (v + 0.044715f * v * v * v);
          v = v / (1.f + __expf(-u));
          outB[idx] = f2bf(v);
        } else {  // MODE 4
          float o;
          if (colg < 1024)
            o = (v >= 0.f) ? (v + 0.5f) : (1.f / (1.f + __expf(-v)));  // g(hidden)
          else
            o = 1.f / (1.f + __expf(v));                               // sigmoid(-gate)
          outB[idx] = f2bf(o);
        }
      }
    }
  }
}

// ---------------- minGRU linear-space chunked scan (pure FMA) ----------------
// hg layout: [T][2048], col<1024: ghid, col>=1024: a. h_t = a h_{t-1} + (1-a) ghid.
__global__ __launch_bounds__(256) void scan_p1(const ushort* __restrict__ hg,
                                               float* __restrict__ Ag,
                                               float* __restrict__ Bg) {
  int blk = blockIdx.x;
  int dt = blk & 3, ch = (blk >> 2) & 31, b = blk >> 7;
  int d = (dt << 8) + threadIdx.x;
  const ushort* p = hg + (size_t)(b * L_ + ch * CHL) * 2048 + d;
  float A = 1.f, Bv = 0.f;
  for (int s = 0; s < CHL; ++s) {
    float g = bf2f(p[0]), a = bf2f(p[1024]);
    p += 2048;
    A *= a;
    Bv = fmaf(a, Bv, (1.f - a) * g);
  }
  size_t o = (size_t)((b * NCH + ch) * D_) + d;
  Ag[o] = A; Bg[o] = Bv;
}

__global__ __launch_bounds__(256) void scan_p2(const float* __restrict__ Ag,
                                               const float* __restrict__ Bg,
                                               float* __restrict__ Pre) {
  int dt = blockIdx.x & 3, b = blockIdx.x >> 2;
  int d = (dt << 8) + threadIdx.x;
  float h = 0.f;
  for (int c = 0; c < NCH; ++c) {
    size_t i = (size_t)((b * NCH + c) * D_) + d;
    Pre[i] = h;
    h = fmaf(Ag[i], h, Bg[i]);
  }
}

__global__ __launch_bounds__(256) void scan_p3(const ushort* __restrict__ hg,
                                               const float* __restrict__ Pre,
                                               float* __restrict__ xio,
                                               float* __restrict__ nh) {
  int blk = blockIdx.x;
  int dt = blk & 3, ch = (blk >> 2) & 31, b = blk >> 7;
  int d = (dt << 8) + threadIdx.x;
  const ushort* p = hg + (size_t)(b * L_ + ch * CHL) * 2048 + d;
  float* q = xio + (size_t)(b * L_ + ch * CHL) * D_ + d;
  float h = Pre[(size_t)((b * NCH + ch) * D_) + d];
  for (int s = 0; s < CHL; ++s) {
    float g = bf2f(p[0]), a = bf2f(p[1024]);
    p += 2048;
    h = fmaf(a, h, (1.f - a) * g);
    *q = h + *q;
    q += D_;
  }
  if (ch == NCH - 1) nh[(b << 10) + d] = h;
}

// ---------------- launcher ----------------
extern "C" void kernel_launch(void* const* d_in, const int* in_sizes, int n_in,
                              void* d_out, int out_size, void* d_ws, size_t ws_size,
                              hipStream_t stream) {
  const float* x   = (const float*)d_in[0];
  const float* cdw = (const float*)d_in[1];
  const float* cdb = (const float*)d_in[2];
  const float* cpw = (const float*)d_in[3];
  const float* cpb = (const float*)d_in[4];
  const float* cng = (const float*)d_in[5];
  const float* gng = (const float*)d_in[6];
  const float* gw  = (const float*)d_in[7];
  const float* fng = (const float*)d_in[8];
  const float* fw1 = (const float*)d_in[9];
  const float* fb1 = (const float*)d_in[10];
  const float* fw2 = (const float*)d_in[11];
  const float* fb2 = (const float*)d_in[12];
  float* out = (float*)d_out;
  char* ws = (char*)d_ws;

  // workspace layout (bytes)
  ushort* wpw_b = (ushort*)(ws + 0);          //  2 MiB
  ushort* wgr_b = (ushort*)(ws + 2097152);    //  4 MiB
  ushort* wf1_b = (ushort*)(ws + 6291456);    //  8 MiB
  ushort* wf2_b = (ushort*)(ws + 14680064);   //  8 MiB
  float*  Ag    = (float*) (ws + 23134208);   // 512 KiB
  float*  Bg    = (float*) (ws + 23658496);   // 512 KiB
  float*  Pre   = (float*) (ws + 24182784);   // 512 KiB
  ushort* zbuf  = (ushort*)(ws + 24707072);   // 32 MiB (y / z1 / z2, reused)
  ushort* hg    = (ushort*)(ws + 58261504);   // 64 MiB bf16 [T][2048] (ghid | a)
  ushort* h1    = (ushort*)(ws + 58261504);   // 128 MiB bf16 [T][4096] (overlays hg)
  float*  nh    = out + (size_t)T_ * D_;      // next_hidden tail of d_out

  // weights -> bf16
  cvt_bf<<<dim3(1024), 256, 0, stream>>>(cpw, wpw_b, 262144);
  cvt_bf<<<dim3(2048), 256, 0, stream>>>(gw,  wgr_b, 524288);
  cvt_bf<<<dim3(4096), 256, 0, stream>>>(fw1, wf1_b, 1048576);
  cvt_bf<<<dim3(4096), 256, 0, stream>>>(fw2, wf2_b, 1048576);

  // stage 1: fused rmsnorm + causal dwconv -> y (bf16); x1 = y@Wpw^T + b + x
  dwconv_k<<<dim3(T_), 256, 0, stream>>>(x, cdw, cdb, cng, zbuf);
  gemm256<0><<<dim3(4, 64), 512, 0, stream>>>(zbuf, wpw_b, cpb, x, out, nullptr, T_, 1024, 1024);

  // stage 2: z1 = rmsnorm(x1)*g; hg = gate-transform(z1 @ Wgru^T); scan; x2 = h + x1
  rms_scale<<<dim3(T_), 256, 0, stream>>>(out, gng, zbuf);
  gemm256<4><<<dim3(8, 64), 512, 0, stream>>>(zbuf, wgr_b, nullptr, nullptr, nullptr, hg, T_, 2048, 1024);
  scan_p1<<<dim3(512), 256, 0, stream>>>(hg, Ag, Bg);
  scan_p2<<<dim3(16), 256, 0, stream>>>(Ag, Bg, Pre);
  scan_p3<<<dim3(512), 256, 0, stream>>>(hg, Pre, out, nh);

  // stage 3: z2 = rmsnorm(x2)*g; h1 = gelu(z2@W1^T + b1); out = h1@W2^T + b2 + x2
  rms_scale<<<dim3(T_), 256, 0, stream>>>(out, fng, zbuf);
  gemm256<2><<<dim3(16, 64), 512, 0, stream>>>(zbuf, wf1_b, fb1, nullptr, nullptr, h1, T_, 4096, 1024);
  gemm256<0><<<dim3(4, 64), 512, 0, stream>>>(h1, wf2_b, fb2, out, out, nullptr, T_, 1024, 4096);
}

// Round 6
// 927.352 us; speedup vs baseline: 1.9399x; 1.9399x over previous
//
#include <hip/hip_runtime.h>

typedef __attribute__((ext_vector_type(8))) short short8;
typedef __attribute__((ext_vector_type(4))) float floatx4;

#define D_   1024
#define L_   4096
#define B_   4
#define T_   16384
#define NCH  32     // scan chunks per sequence
#define CHL  128    // scan chunk length

__device__ __forceinline__ ushort f2bf(float f) {
  unsigned u = __float_as_uint(f);
  u += 0x7fffu + ((u >> 16) & 1u);   // round-to-nearest-even
  return (ushort)(u >> 16);
}
__device__ __forceinline__ float bf2f(ushort u) {
  return __uint_as_float(((unsigned)u) << 16);
}

// async global->LDS, 16B per lane. LDS dest MUST be wave-uniform base + lane*16.
__device__ __forceinline__ void gl2lds(const ushort* g, ushort* l) {
  __builtin_amdgcn_global_load_lds(
      (const __attribute__((address_space(1))) unsigned int*)g,
      (__attribute__((address_space(3))) unsigned int*)l, 16, 0, 0);
}

// ---------------- weight fp32 -> bf16 ----------------
__global__ __launch_bounds__(256) void cvt_bf(const float* __restrict__ s,
                                              ushort* __restrict__ d, int n4) {
  int i = blockIdx.x * 256 + threadIdx.x;
  if (i >= n4) return;
  float4 v = ((const float4*)s)[i];
  ushort4 o;
  o.x = f2bf(v.x); o.y = f2bf(v.y); o.z = f2bf(v.z); o.w = f2bf(v.w);
  ((ushort4*)d)[i] = o;
}

// ---------------- fused rmsnorm + gamma-scale -> bf16 (stages 2,3) ----------------
__global__ __launch_bounds__(256) void rms_scale(const float* __restrict__ x,
                                                 const float* __restrict__ g,
                                                 ushort* __restrict__ z) {
  int t = blockIdx.x;
  float4 v = ((const float4*)(x + (size_t)t * D_))[threadIdx.x];
  float s = v.x * v.x + v.y * v.y + v.z * v.z + v.w * v.w;
#pragma unroll
  for (int off = 32; off > 0; off >>= 1) s += __shfl_xor(s, off, 64);
  __shared__ float red[4];
  if ((threadIdx.x & 63) == 0) red[threadIdx.x >> 6] = s;
  __syncthreads();
  float iv = 32.0f / fmaxf(sqrtf(red[0] + red[1] + red[2] + red[3]), 1e-12f);
  float4 gg = ((const float4*)g)[threadIdx.x];
  ushort4 o;
  o.x = f2bf(v.x * iv * (gg.x + 1.f));
  o.y = f2bf(v.y * iv * (gg.y + 1.f));
  o.z = f2bf(v.z * iv * (gg.z + 1.f));
  o.w = f2bf(v.w * iv * (gg.w + 1.f));
  ((ushort4*)(z + (size_t)t * D_))[threadIdx.x] = o;
}

// ---------------- fused rmsnorm (3 norms in-block) + causal dwconv (K=3) ----------------
__global__ __launch_bounds__(256) void dwconv_k(const float* __restrict__ x,
                                                const float* __restrict__ wdw,
                                                const float* __restrict__ bdw,
                                                const float* __restrict__ gm,
                                                ushort* __restrict__ y) {
  int t = blockIdx.x;
  int c4 = threadIdx.x << 2;
  int l = t & (L_ - 1);
  const float* p0 = x + (size_t)t * D_ + c4;
  float4 v0 = *(const float4*)p0;
  float4 v1 = {0.f, 0.f, 0.f, 0.f}, v2 = {0.f, 0.f, 0.f, 0.f};
  if (l >= 1) v1 = *(const float4*)(p0 - D_);
  if (l >= 2) v2 = *(const float4*)(p0 - 2 * D_);
  float s0 = v0.x * v0.x + v0.y * v0.y + v0.z * v0.z + v0.w * v0.w;
  float s1 = v1.x * v1.x + v1.y * v1.y + v1.z * v1.z + v1.w * v1.w;
  float s2 = v2.x * v2.x + v2.y * v2.y + v2.z * v2.z + v2.w * v2.w;
#pragma unroll
  for (int off = 32; off > 0; off >>= 1) {
    s0 += __shfl_xor(s0, off, 64);
    s1 += __shfl_xor(s1, off, 64);
    s2 += __shfl_xor(s2, off, 64);
  }
  __shared__ float r0[4], r1[4], r2[4];
  if ((threadIdx.x & 63) == 0) {
    int w = threadIdx.x >> 6;
    r0[w] = s0; r1[w] = s1; r2[w] = s2;
  }
  __syncthreads();
  float i0 = 32.0f / fmaxf(sqrtf(r0[0] + r0[1] + r0[2] + r0[3]), 1e-12f);
  float i1 = 32.0f / fmaxf(sqrtf(r1[0] + r1[1] + r1[2] + r1[3]), 1e-12f);
  float i2 = 32.0f / fmaxf(sqrtf(r2[0] + r2[1] + r2[2] + r2[3]), 1e-12f);
  float a0[4] = {v0.x, v0.y, v0.z, v0.w};
  float a1[4] = {v1.x, v1.y, v1.z, v1.w};
  float a2[4] = {v2.x, v2.y, v2.z, v2.w};
  ushort r[4];
#pragma unroll
  for (int j = 0; j < 4; ++j) {
    int d = c4 + j;
    float w0 = wdw[d * 3 + 0], w1 = wdw[d * 3 + 1], w2 = wdw[d * 3 + 2];
    float s = w2 * a0[j] * i0 + w1 * a1[j] * i1 + w0 * a2[j] * i2;
    s = s * (gm[d] + 1.0f) + bdw[d];
    r[j] = f2bf(s);
  }
  ushort4 o; o.x = r[0]; o.y = r[1]; o.z = r[2]; o.w = r[3];
  *(ushort4*)(y + (size_t)t * D_ + c4) = o;
}

// ---------------- 256x256 8-phase bf16 MFMA GEMM (lookahead-pipelined) ----------------
// A: [M][K] bf16 row-major, W: [N][K] bf16 row-major. C = A @ W^T.
// 512 threads = 8 waves (2M x 4N); per-wave 128x64 output; BK=64; 128 KiB LDS dbuf.
// r6 mechanism: each phase issues ds_reads for the NEXT quadrant's operands into
// ALIASED arrays (avLo/avHi/bLo/bHi = 96 VGPR, no double-buffer -> no r5 spill).
// Counted lgkmcnt(4/8) drains exactly the consuming cluster's operands and leaves
// the lookahead reads in flight -> LDS read service (85 B/cyc, ~4500cyc/2tiles)
// overlaps the 621-cyc MFMA clusters instead of serializing with them.
// One WAR cycle (bLo written P7 / consumed P8) resolved by issuing that read set
// AFTER P8's MFMA cluster (data dep keeps compiler from hoisting it).
// LDS swizzle: stored k-slot = logical ^ (row&7); pre-swizzled global source,
// linear global_load_lds dest; matching XOR on ds_read side -> 0 bank conflicts.
// vmcnt ledger (per 2-tile iter, entry invariant 4 outstanding = B(m+1)):
//  P1 +2(A m+1 h0)=6  P2 +2(h1)=8  P3 +4(B m+2)=12 -> P4 vmcnt(4): lands
//  B(m+1)+A(m+1) (buf1 ready), leaves B(m+2).  P5 +2  P6 +2  P7 +4(B m+3)=12 ->
//  vmcnt(4): lands B(m+2)+A(m+2) (buf0 ready), leaves B(m+3) = invariant.
// lgkm ledger: P1(16)->4  P2(12)->8  P3(8)->0  P5(16)->4  P6(12)->8  P7(16)->8.
// MODE 0: outF = acc + bias + resid. MODE 2: outB = bf16(gelu(acc+bias)).
// MODE 4: minGRU gates: col<1024 -> g(acc); col>=1024 -> sigmoid(-acc).

#define DS_A(DST, PB, MQ)                                                    \
  _Pragma("unroll") for (int mf_ = 0; mf_ < 4; ++mf_) {                      \
    DST[2 * mf_]     = *(const short8*)((PB) + (MQ) + mf_ * 1024 + o0);      \
    DST[2 * mf_ + 1] = *(const short8*)((PB) + (MQ) + mf_ * 1024 + o1);      \
  }

#define DS_B4(DST, PB, NH)                                                   \
  _Pragma("unroll") for (int nf_ = 0; nf_ < 2; ++nf_) {                      \
    DST[2 * nf_]     = *(const short8*)((PB) + (NH) * 2048 + nf_ * 1024 + o0); \
    DST[2 * nf_ + 1] = *(const short8*)((PB) + (NH) * 2048 + nf_ * 1024 + o1); \
  }

#define MFMA_Q2(AS, BS, MB, NB)                                              \
  __builtin_amdgcn_s_setprio(1);                                             \
  _Pragma("unroll") for (int mf_ = 0; mf_ < 4; ++mf_) {                      \
    _Pragma("unroll") for (int nf_ = 0; nf_ < 2; ++nf_) {                    \
      floatx4 c_ = acc[(MB) + mf_][(NB) + nf_];                              \
      c_ = __builtin_amdgcn_mfma_f32_16x16x32_bf16(AS[2 * mf_],              \
             BS[2 * nf_], c_, 0, 0, 0);                                      \
      c_ = __builtin_amdgcn_mfma_f32_16x16x32_bf16(AS[2 * mf_ + 1],          \
             BS[2 * nf_ + 1], c_, 0, 0, 0);                                  \
      acc[(MB) + mf_][(NB) + nf_] = c_;                                      \
    }                                                                        \
  }                                                                          \
  __builtin_amdgcn_s_setprio(0)

#define SBAR()  asm volatile("s_barrier" ::: "memory")
#define SCHED() __builtin_amdgcn_sched_barrier(0)
#define LGKM(N) asm volatile("s_waitcnt lgkmcnt(" #N ")" ::: "memory")
#define VMC(N)  asm volatile("s_waitcnt vmcnt(" #N ")" ::: "memory")

template <int MODE>
__global__ __launch_bounds__(512, 2) void gemm256(
    const ushort* __restrict__ A, const ushort* __restrict__ W,
    const float* __restrict__ bias, const float* __restrict__ resid,
    float* __restrict__ outF, ushort* __restrict__ outB, int M, int N, int K) {
  __shared__ ushort lds[65536];  // 128 KiB: buf{0,1} x (A[256][64] | B[256][64])
  const int tid = threadIdx.x;

  // --- XCD-aware bijective remap (gridDim.y == 64, nx power of 2 -> nwg%8==0) ---
  const int nx = gridDim.x;
  const int lxs = 31 - __clz(nx);
  const int lin = blockIdx.x + blockIdx.y * nx;
  const int cpx = nx << 3;                 // nwg/8 = nx*64/8
  const int wg = (lin & 7) * cpx + (lin >> 3);
  const int bm = (wg >> lxs) << 8;
  const int bn = (wg & (nx - 1)) << 8;

  const int lane = tid & 63, wave = tid >> 6;
  const int wm = (wave >> 2) & 1;          // M half of the tile
  const int wn = wave & 3;                 // N quarter
  const int fr = lane & 15, fq = lane >> 4;

  // staging: thread t -> row srow (64 rows/round), swizzled k-slot source
  const int srow = tid >> 3;               // 0..63
  const int kcs = (tid & 7) ^ (srow & 7);  // pre-swizzled global k-slot
  const ushort* gA = A + (size_t)(bm + srow) * K + kcs * 8;
  const ushort* gB = W + (size_t)(bn + srow) * K + kcs * 8;
  ushort* ldst = lds + tid * 8;            // linear LDS dest (lane*16B)

  // read-side bases (swizzled slot = j ^ (fr&7), j = ks*4 + fq)
  const ushort* pA0 = lds + (size_t)(wm * 128 + fr) * 64;
  const ushort* pB0 = lds + 16384 + (size_t)(wn * 64 + fr) * 64;
  const ushort* pA1 = pA0 + 32768;
  const ushort* pB1 = pB0 + 32768;
  const int o0 = (fq ^ (fr & 7)) * 8;
  const int o1 = o0 ^ 32;

  floatx4 acc[8][4];
#pragma unroll
  for (int i = 0; i < 8; ++i)
#pragma unroll
    for (int j = 0; j < 4; ++j) acc[i][j] = {0.f, 0.f, 0.f, 0.f};
  // aliased fragment arrays (96 VGPR total): no per-tile duplication
  short8 avLo[8], avHi[8];
  short8 bLo[4], bHi[4];

  auto stageA = [&](int buf, int half, int kt) {
    const ushort* s = gA + (size_t)(half * 128) * K + kt * 64;
    ushort* d = ldst + buf * 32768 + half * 8192;
    gl2lds(s, d);
    gl2lds(s + (size_t)64 * K, d + 4096);
  };
  auto stageB = [&](int buf, int half, int kt) {
    const ushort* s = gB + (size_t)(half * 128) * K + kt * 64;
    ushort* d = ldst + buf * 32768 + 16384 + half * 8192;
    gl2lds(s, d);
    gl2lds(s + (size_t)64 * K, d + 4096);
  };

  const int nt = K >> 6;  // K-tiles of 64 (even: 16 or 64 here)

  // prologue: tile0 {A,B} + tile1 {B}; land tile0 (tile1.B stays in flight)
  stageA(0, 0, 0); stageA(0, 1, 0);
  stageB(0, 0, 0); stageB(0, 1, 0);
  stageB(1, 0, 1); stageB(1, 1, 1);
  VMC(4);
  SBAR(); SCHED();
  DS_A(avLo, pA0, 0);                 // tile0 A quad-lo   (12 lgkm pending
  DS_B4(bLo, pB0, 0);                 // tile0 B cols 0-31  into P1)

  for (int m = 0; m < nt; m += 2) {
    const bool more = (m + 2 < nt);
    // ====== tile m (buf0): Q00 Q01 Q11 Q10 ======
    // P1: Q00_E; lookahead bHi_E
    DS_B4(bHi, pB0, 1);
    stageA(1, 0, m + 1);
    SBAR(); LGKM(4); SCHED();          // drain avLo_E,bLo_E; bHi in flight
    MFMA_Q2(avLo, bLo, 0, 0);
    SBAR(); SCHED();
    // P2: Q01_E; lookahead avHi_E
    DS_A(avHi, pA0, 4096);
    stageA(1, 1, m + 1);
    SBAR(); LGKM(8); SCHED();          // drain bHi_E; avHi in flight
    MFMA_Q2(avLo, bHi, 0, 2);
    SBAR(); SCHED();
    // P3: Q11_E
    if (more) { stageB(0, 0, m + 2); stageB(0, 1, m + 2); }
    SBAR(); LGKM(0); SCHED();          // drain avHi_E
    MFMA_Q2(avHi, bHi, 4, 2);
    SBAR(); SCHED();
    // P4: Q10_E; buf1 landed -> lookahead avLo_O
    if (more) { VMC(4); } else { VMC(0); }
    SBAR(); SCHED();                   // all waves' DMA landed
    DS_A(avLo, pA1, 0);
    MFMA_Q2(avHi, bLo, 4, 0);
    SBAR(); SCHED();
    // ====== tile m+1 (buf1) ======
    // P5: Q00_O; in-phase bLo_O + lookahead bHi_O
    DS_B4(bLo, pB1, 0);
    DS_B4(bHi, pB1, 1);
    if (more) stageA(0, 0, m + 2);
    SBAR(); LGKM(4); SCHED();          // drain avLo_O,bLo_O; bHi_O in flight
    MFMA_Q2(avLo, bLo, 0, 0);
    SBAR(); SCHED();
    // P6: Q01_O; lookahead avHi_O
    DS_A(avHi, pA1, 4096);
    if (more) stageA(0, 1, m + 2);
    SBAR(); LGKM(8); SCHED();          // drain bHi_O; avHi_O in flight
    MFMA_Q2(avLo, bHi, 0, 2);
    SBAR(); SCHED();
    // P7: Q11_O; buf0(m+2) landed -> lookahead avLo_E'
    if (more) {
      stageB(1, 0, m + 3); stageB(1, 1, m + 3);
      VMC(4);
    } else {
      VMC(0);
    }
    SBAR(); SCHED();
    if (more) {
      DS_A(avLo, pA0, 0);
      LGKM(8);                         // drain avHi_O; avLo_E' in flight
    } else {
      LGKM(0);
    }
    SCHED();
    MFMA_Q2(avHi, bHi, 4, 2);
    SBAR(); SCHED();
    // P8: Q10_O; post-MFMA read bLo_E' (WAR: bLo consumed by this cluster)
    MFMA_Q2(avHi, bLo, 4, 0);
    if (more) { DS_B4(bLo, pB0, 0); }
    SBAR(); SCHED();
  }

  // ---------------- epilogue ----------------
  const int rowb = bm + wm * 128 + fq * 4;
  const int colb = bn + wn * 64 + fr;
#pragma unroll
  for (int nf = 0; nf < 4; ++nf) {
    const int colg = colb + nf * 16;
    const float bvs = (MODE == 4) ? 0.f : bias[colg];
#pragma unroll
    for (int mf = 0; mf < 8; ++mf) {
#pragma unroll
      for (int r = 0; r < 4; ++r) {
        const int rowg = rowb + mf * 16 + r;
        const size_t idx = (size_t)rowg * N + colg;
        float v = acc[mf][nf][r];
        if (MODE == 0) {
          outF[idx] = v + bvs + resid[idx];
        } else if (MODE == 2) {
          v += bvs;
          // gelu(x) ~= x * sigmoid(1.5957691(x + 0.044715 x^3)); maxerr ~1e-3
          float u = 1.5957691216f * (v + 0.044715f * v * v * v);
          v = v / (1.f + __expf(-u));
          outB[idx] = f2bf(v);
        } else {  // MODE 4
          float o;
          if (colg < 1024)
            o = (v >= 0.f) ? (v + 0.5f) : (1.f / (1.f + __expf(-v)));  // g(hidden)
          else
            o = 1.f / (1.f + __expf(v));                               // sigmoid(-gate)
          outB[idx] = f2bf(o);
        }
      }
    }
  }
}

// ---------------- minGRU linear-space chunked scan (pure FMA) ----------------
// hg layout: [T][2048], col<1024: ghid, col>=1024: a. h_t = a h_{t-1} + (1-a) ghid.
__global__ __launch_bounds__(256) void scan_p1(const ushort* __restrict__ hg,
                                               float* __restrict__ Ag,
                                               float* __restrict__ Bg) {
  int blk = blockIdx.x;
  int dt = blk & 3, ch = (blk >> 2) & 31, b = blk >> 7;
  int d = (dt << 8) + threadIdx.x;
  const ushort* p = hg + (size_t)(b * L_ + ch * CHL) * 2048 + d;
  float A = 1.f, Bv = 0.f;
  for (int s = 0; s < CHL; ++s) {
    float g = bf2f(p[0]), a = bf2f(p[1024]);
    p += 2048;
    A *= a;
    Bv = fmaf(a, Bv, (1.f - a) * g);
  }
  size_t o = (size_t)((b * NCH + ch) * D_) + d;
  Ag[o] = A; Bg[o] = Bv;
}

__global__ __launch_bounds__(256) void scan_p2(const float* __restrict__ Ag,
                                               const float* __restrict__ Bg,
                                               float* __restrict__ Pre) {
  int dt = blockIdx.x & 3, b = blockIdx.x >> 2;
  int d = (dt << 8) + threadIdx.x;
  float h = 0.f;
  for (int c = 0; c < NCH; ++c) {
    size_t i = (size_t)((b * NCH + c) * D_) + d;
    Pre[i] = h;
    h = fmaf(Ag[i], h, Bg[i]);
  }
}

__global__ __launch_bounds__(256) void scan_p3(const ushort* __restrict__ hg,
                                               const float* __restrict__ Pre,
                                               float* __restrict__ xio,
                                               float* __restrict__ nh) {
  int blk = blockIdx.x;
  int dt = blk & 3, ch = (blk >> 2) & 31, b = blk >> 7;
  int d = (dt << 8) + threadIdx.x;
  const ushort* p = hg + (size_t)(b * L_ + ch * CHL) * 2048 + d;
  float* q = xio + (size_t)(b * L_ + ch * CHL) * D_ + d;
  float h = Pre[(size_t)((b * NCH + ch) * D_) + d];
  for (int s = 0; s < CHL; ++s) {
    float g = bf2f(p[0]), a = bf2f(p[1024]);
    p += 2048;
    h = fmaf(a, h, (1.f - a) * g);
    *q = h + *q;
    q += D_;
  }
  if (ch == NCH - 1) nh[(b << 10) + d] = h;
}

// ---------------- launcher ----------------
extern "C" void kernel_launch(void* const* d_in, const int* in_sizes, int n_in,
                              void* d_out, int out_size, void* d_ws, size_t ws_size,
                              hipStream_t stream) {
  const float* x   = (const float*)d_in[0];
  const float* cdw = (const float*)d_in[1];
  const float* cdb = (const float*)d_in[2];
  const float* cpw = (const float*)d_in[3];
  const float* cpb = (const float*)d_in[4];
  const float* cng = (const float*)d_in[5];
  const float* gng = (const float*)d_in[6];
  const float* gw  = (const float*)d_in[7];
  const float* fng = (const float*)d_in[8];
  const float* fw1 = (const float*)d_in[9];
  const float* fb1 = (const float*)d_in[10];
  const float* fw2 = (const float*)d_in[11];
  const float* fb2 = (const float*)d_in[12];
  float* out = (float*)d_out;
  char* ws = (char*)d_ws;

  // workspace layout (bytes)
  ushort* wpw_b = (ushort*)(ws + 0);          //  2 MiB
  ushort* wgr_b = (ushort*)(ws + 2097152);    //  4 MiB
  ushort* wf1_b = (ushort*)(ws + 6291456);    //  8 MiB
  ushort* wf2_b = (ushort*)(ws + 14680064);   //  8 MiB
  float*  Ag    = (float*) (ws + 23134208);   // 512 KiB
  float*  Bg    = (float*) (ws + 23658496);   // 512 KiB
  float*  Pre   = (float*) (ws + 24182784);   // 512 KiB
  ushort* zbuf  = (ushort*)(ws + 24707072);   // 32 MiB (y / z1 / z2, reused)
  ushort* hg    = (ushort*)(ws + 58261504);   // 64 MiB bf16 [T][2048] (ghid | a)
  ushort* h1    = (ushort*)(ws + 58261504);   // 128 MiB bf16 [T][4096] (overlays hg)
  float*  nh    = out + (size_t)T_ * D_;      // next_hidden tail of d_out

  // weights -> bf16
  cvt_bf<<<dim3(1024), 256, 0, stream>>>(cpw, wpw_b, 262144);
  cvt_bf<<<dim3(2048), 256, 0, stream>>>(gw,  wgr_b, 524288);
  cvt_bf<<<dim3(4096), 256, 0, stream>>>(fw1, wf1_b, 1048576);
  cvt_bf<<<dim3(4096), 256, 0, stream>>>(fw2, wf2_b, 1048576);

  // stage 1: fused rmsnorm + causal dwconv -> y (bf16); x1 = y@Wpw^T + b + x
  dwconv_k<<<dim3(T_), 256, 0, stream>>>(x, cdw, cdb, cng, zbuf);
  gemm256<0><<<dim3(4, 64), 512, 0, stream>>>(zbuf, wpw_b, cpb, x, out, nullptr, T_, 1024, 1024);

  // stage 2: z1 = rmsnorm(x1)*g; hg = gate-transform(z1 @ Wgru^T); scan; x2 = h + x1
  rms_scale<<<dim3(T_), 256, 0, stream>>>(out, gng, zbuf);
  gemm256<4><<<dim3(8, 64), 512, 0, stream>>>(zbuf, wgr_b, nullptr, nullptr, nullptr, hg, T_, 2048, 1024);
  scan_p1<<<dim3(512), 256, 0, stream>>>(hg, Ag, Bg);
  scan_p2<<<dim3(16), 256, 0, stream>>>(Ag, Bg, Pre);
  scan_p3<<<dim3(512), 256, 0, stream>>>(hg, Pre, out, nh);

  // stage 3: z2 = rmsnorm(x2)*g; h1 = gelu(z2@W1^T + b1); out = h1@W2^T + b2 + x2
  rms_scale<<<dim3(T_), 256, 0, stream>>>(out, fng, zbuf);
  gemm256<2><<<dim3(16, 64), 512, 0, stream>>>(zbuf, wf1_b, fb1, nullptr, nullptr, h1, T_, 4096, 1024);
  gemm256<0><<<dim3(4, 64), 512, 0, stream>>>(h1, wf2_b, fb2, out, out, nullptr, T_, 1024, 4096);
}

// Round 7
// 711.885 us; speedup vs baseline: 2.5270x; 1.3027x over previous
//
#include <hip/hip_runtime.h>

typedef __attribute__((ext_vector_type(8))) short short8;
typedef __attribute__((ext_vector_type(4))) float floatx4;

#define D_   1024
#define L_   4096
#define B_   4
#define T_   16384
#define NCH  32     // scan chunks per sequence
#define CHL  128    // scan chunk length

__device__ __forceinline__ ushort f2bf(float f) {
  unsigned u = __float_as_uint(f);
  u += 0x7fffu + ((u >> 16) & 1u);   // round-to-nearest-even
  return (ushort)(u >> 16);
}
__device__ __forceinline__ float bf2f(ushort u) {
  return __uint_as_float(((unsigned)u) << 16);
}

// async global->LDS, 16B per lane. LDS dest MUST be wave-uniform base + lane*16.
__device__ __forceinline__ void gl2lds(const ushort* g, ushort* l) {
  __builtin_amdgcn_global_load_lds(
      (const __attribute__((address_space(1))) unsigned int*)g,
      (__attribute__((address_space(3))) unsigned int*)l, 16, 0, 0);
}

// ---------------- all weights fp32 -> bf16 in ONE launch ----------------
// segments (float4 units): cpw 262144 | gw 524288 | fw1 1048576 | fw2 1048576
__global__ __launch_bounds__(256) void cvt_all(
    const float* __restrict__ s0, ushort* __restrict__ d0,
    const float* __restrict__ s1, ushort* __restrict__ d1,
    const float* __restrict__ s2, ushort* __restrict__ d2,
    const float* __restrict__ s3, ushort* __restrict__ d3) {
  int j = blockIdx.x * 256 + threadIdx.x;
  const float* s; ushort* d;
  if (j < 262144) { s = s0; d = d0; }
  else if ((j -= 262144) < 524288) { s = s1; d = d1; }
  else if ((j -= 524288) < 1048576) { s = s2; d = d2; }
  else { j -= 1048576; s = s3; d = d3; }
  float4 v = ((const float4*)s)[j];
  ushort4 o;
  o.x = f2bf(v.x); o.y = f2bf(v.y); o.z = f2bf(v.z); o.w = f2bf(v.w);
  ((ushort4*)d)[j] = o;
}

// ---------------- fused rmsnorm + gamma-scale -> bf16 (stages 2,3) ----------------
__global__ __launch_bounds__(256) void rms_scale(const float* __restrict__ x,
                                                 const float* __restrict__ g,
                                                 ushort* __restrict__ z) {
  int t = blockIdx.x;
  float4 v = ((const float4*)(x + (size_t)t * D_))[threadIdx.x];
  float s = v.x * v.x + v.y * v.y + v.z * v.z + v.w * v.w;
#pragma unroll
  for (int off = 32; off > 0; off >>= 1) s += __shfl_xor(s, off, 64);
  __shared__ float red[4];
  if ((threadIdx.x & 63) == 0) red[threadIdx.x >> 6] = s;
  __syncthreads();
  float iv = 32.0f / fmaxf(sqrtf(red[0] + red[1] + red[2] + red[3]), 1e-12f);
  float4 gg = ((const float4*)g)[threadIdx.x];
  ushort4 o;
  o.x = f2bf(v.x * iv * (gg.x + 1.f));
  o.y = f2bf(v.y * iv * (gg.y + 1.f));
  o.z = f2bf(v.z * iv * (gg.z + 1.f));
  o.w = f2bf(v.w * iv * (gg.w + 1.f));
  ((ushort4*)(z + (size_t)t * D_))[threadIdx.x] = o;
}

// ---------------- fused rmsnorm + causal dwconv (K=3), 4 timesteps/block ----------------
// Block handles t0..t0+3 (one sequence chunk; L%4==0). Loads 6 rows (2-halo) ->
// 1.5x read/row instead of 3x. 6 in-block rmsnorms via parallel shuffle-reduce.
__global__ __launch_bounds__(256) void dwconv_k(const float* __restrict__ x,
                                                const float* __restrict__ wdw,
                                                const float* __restrict__ bdw,
                                                const float* __restrict__ gm,
                                                ushort* __restrict__ y) {
  int t0 = blockIdx.x << 2;
  int c4 = threadIdx.x << 2;
  int l0 = t0 & (L_ - 1);
  const float* base = x + (size_t)t0 * D_ + c4;
  float a[6][4];
  float s[6];
#pragma unroll
  for (int k = 0; k < 6; ++k) {
    int off = k - 2;                       // rows t0-2 .. t0+3
    if (l0 + off >= 0) {                   // only l0==0 masks (l0 multiple of 4)
      float4 v = *(const float4*)(base + (ptrdiff_t)off * D_);
      a[k][0] = v.x; a[k][1] = v.y; a[k][2] = v.z; a[k][3] = v.w;
    } else {
      a[k][0] = a[k][1] = a[k][2] = a[k][3] = 0.f;
    }
    s[k] = a[k][0] * a[k][0] + a[k][1] * a[k][1] + a[k][2] * a[k][2] + a[k][3] * a[k][3];
  }
#pragma unroll
  for (int off = 32; off > 0; off >>= 1) {
#pragma unroll
    for (int k = 0; k < 6; ++k) s[k] += __shfl_xor(s[k], off, 64);
  }
  __shared__ float red[6][4];
  if ((threadIdx.x & 63) == 0) {
    int w = threadIdx.x >> 6;
#pragma unroll
    for (int k = 0; k < 6; ++k) red[k][w] = s[k];
  }
  __syncthreads();
  float inv[6];
#pragma unroll
  for (int k = 0; k < 6; ++k)
    inv[k] = 32.0f / fmaxf(sqrtf(red[k][0] + red[k][1] + red[k][2] + red[k][3]), 1e-12f);

  float w0[4], w1[4], w2[4], gmd[4], bdd[4];
#pragma unroll
  for (int jj = 0; jj < 4; ++jj) {
    int d = c4 + jj;
    w0[jj] = wdw[d * 3 + 0]; w1[jj] = wdw[d * 3 + 1]; w2[jj] = wdw[d * 3 + 2];
    gmd[jj] = gm[d] + 1.0f;  bdd[jj] = bdw[d];
  }
#pragma unroll
  for (int j = 0; j < 4; ++j) {            // output row t0+j uses rows j+2,j+1,j
    ushort r[4];
#pragma unroll
    for (int jj = 0; jj < 4; ++jj) {
      float v = w2[jj] * a[j + 2][jj] * inv[j + 2] +
                w1[jj] * a[j + 1][jj] * inv[j + 1] +
                w0[jj] * a[j][jj] * inv[j];
      r[jj] = f2bf(v * gmd[jj] + bdd[jj]);
    }
    ushort4 o; o.x = r[0]; o.y = r[1]; o.z = r[2]; o.w = r[3];
    *(ushort4*)(y + (size_t)(t0 + j) * D_ + c4) = o;
  }
}

// ---------------- 256x256 8-phase bf16 MFMA GEMM (r2-verified best) ----------------
// A: [M][K] bf16 row-major, W: [N][K] bf16 row-major. C = A @ W^T.
// 512 threads = 8 waves (2M x 4N); per-wave 128x64 output; BK=64; 128 KiB LDS dbuf.
// LDS swizzle: k-slot s holds global slot s ^ (row&7) (pre-swizzled global src,
// linear global_load_lds dest; matching XOR on ds_read side -> 0 bank conflicts).
// MODE 0: outF = acc + bias + resid (fp32).
// MODE 2: outB = bf16(gelu(acc + bias)).
// MODE 4: minGRU gate transform: col<1024 -> g(acc); col>=1024 -> sigmoid(-acc).

#define READ_A(BUFO, MQ)                                                      \
  _Pragma("unroll") for (int mf_ = 0; mf_ < 4; ++mf_) {                       \
    av[2 * mf_]     = *(const short8*)(pA + (BUFO) + (MQ) + mf_ * 1024 + o0); \
    av[2 * mf_ + 1] = *(const short8*)(pA + (BUFO) + (MQ) + mf_ * 1024 + o1); \
  }

#define READ_B(BUFO, NH)                                                      \
  _Pragma("unroll") for (int nf_ = 0; nf_ < 2; ++nf_) {                       \
    bv[(NH) * 4 + 2 * nf_] =                                                  \
        *(const short8*)(pB + (BUFO) + (NH) * 2048 + nf_ * 1024 + o0);        \
    bv[(NH) * 4 + 2 * nf_ + 1] =                                              \
        *(const short8*)(pB + (BUFO) + (NH) * 2048 + nf_ * 1024 + o1);        \
  }

#define MFMA_Q(MB, NB)                                                        \
  __builtin_amdgcn_s_setprio(1);                                              \
  _Pragma("unroll") for (int mf_ = 0; mf_ < 4; ++mf_) {                       \
    _Pragma("unroll") for (int nf_ = 0; nf_ < 2; ++nf_) {                     \
      floatx4 c_ = acc[(MB) + mf_][(NB) + nf_];                               \
      c_ = __builtin_amdgcn_mfma_f32_16x16x32_bf16(                           \
          av[2 * mf_], bv[((NB) + nf_) * 2], c_, 0, 0, 0);                    \
      c_ = __builtin_amdgcn_mfma_f32_16x16x32_bf16(                           \
          av[2 * mf_ + 1], bv[((NB) + nf_) * 2 + 1], c_, 0, 0, 0);            \
      acc[(MB) + mf_][(NB) + nf_] = c_;                                       \
    }                                                                         \
  }                                                                           \
  __builtin_amdgcn_s_setprio(0)

#define BAR_LGKM()                                    \
  __builtin_amdgcn_s_barrier();                       \
  asm volatile("s_waitcnt lgkmcnt(0)" ::: "memory");  \
  __builtin_amdgcn_sched_barrier(0)

#define BAR_END()               \
  __builtin_amdgcn_s_barrier(); \
  __builtin_amdgcn_sched_barrier(0)

template <int MODE>
__global__ __launch_bounds__(512, 2) void gemm256(
    const ushort* __restrict__ A, const ushort* __restrict__ W,
    const float* __restrict__ bias, const float* __restrict__ resid,
    float* __restrict__ outF, ushort* __restrict__ outB, int M, int N, int K) {
  __shared__ ushort lds[65536];  // 128 KiB: buf{0,1} x (A[256][64] | B[256][64])
  const int tid = threadIdx.x;

  // --- XCD-aware bijective remap (gridDim.y == 64, nx power of 2 -> nwg%8==0) ---
  const int nx = gridDim.x;
  const int lxs = 31 - __clz(nx);
  const int lin = blockIdx.x + blockIdx.y * nx;
  const int cpx = nx << 3;                 // nwg/8 = nx*64/8
  const int wg = (lin & 7) * cpx + (lin >> 3);
  const int bm = (wg >> lxs) << 8;
  const int bn = (wg & (nx - 1)) << 8;

  const int lane = tid & 63, wave = tid >> 6;
  const int wm = (wave >> 2) & 1;          // M half of the tile
  const int wn = wave & 3;                 // N quarter
  const int fr = lane & 15, fq = lane >> 4;

  // staging: thread t -> row srow (64 rows/round), swizzled k-slot source
  const int srow = tid >> 3;               // 0..63
  const int kcs = (tid & 7) ^ (srow & 7);  // pre-swizzled global k-slot
  const ushort* gA = A + (size_t)(bm + srow) * K + kcs * 8;
  const ushort* gB = W + (size_t)(bn + srow) * K + kcs * 8;
  ushort* ldst = lds + tid * 8;            // linear LDS dest (lane*16B)

  // read-side bases (swizzled slot = j ^ (fr&7), j = ks*4 + fq)
  const ushort* pA = lds + (size_t)(wm * 128 + fr) * 64;
  const ushort* pB = lds + 16384 + (size_t)(wn * 64 + fr) * 64;
  const int o0 = (fq ^ (fr & 7)) * 8;
  const int o1 = o0 ^ 32;

  floatx4 acc[8][4];
#pragma unroll
  for (int i = 0; i < 8; ++i)
#pragma unroll
    for (int j = 0; j < 4; ++j) acc[i][j] = {0.f, 0.f, 0.f, 0.f};
  short8 av[8], bv[8];

  auto stageA = [&](int buf, int half, int kt) {
    const ushort* s = gA + (size_t)(half * 128) * K + kt * 64;
    ushort* d = ldst + buf * 32768 + half * 8192;
    gl2lds(s, d);
    gl2lds(s + (size_t)64 * K, d + 4096);
  };
  auto stageB = [&](int buf, int half, int kt) {
    const ushort* s = gB + (size_t)(half * 128) * K + kt * 64;
    ushort* d = ldst + buf * 32768 + 16384 + half * 8192;
    gl2lds(s, d);
    gl2lds(s + (size_t)64 * K, d + 4096);
  };

  const int nt = K >> 6;  // K-tiles of 64 (even: 16 or 64 here)

  // prologue: tile0 {A,B} + tile1 {B}; wait tile0 (4 loads = tile1.B outstanding)
  stageA(0, 0, 0); stageA(0, 1, 0);
  stageB(0, 0, 0); stageB(0, 1, 0);
  stageB(1, 0, 1); stageB(1, 1, 1);
  asm volatile("s_waitcnt vmcnt(4)" ::: "memory");
  __builtin_amdgcn_s_barrier();
  __builtin_amdgcn_sched_barrier(0);

  for (int m = 0; m < nt; m += 2) {
    const bool more = (m + 2 < nt);
    // ================= tile m (buf0) =================
    READ_A(0, 0);                      // A quad-lo
    READ_B(0, 0);                      // B nf 0-1
    stageA(1, 0, m + 1);
    BAR_LGKM();
    MFMA_Q(0, 0);
    BAR_END();

    READ_B(0, 1);                      // B nf 2-3
    stageA(1, 1, m + 1);
    BAR_LGKM();
    MFMA_Q(0, 2);
    BAR_END();

    READ_A(0, 4096);                   // A quad-hi (buf0.B-lo now free)
    if (more) stageB(0, 0, m + 2);
    BAR_LGKM();
    MFMA_Q(4, 2);
    BAR_END();

    if (more) {
      stageB(0, 1, m + 2);
      asm volatile("s_waitcnt vmcnt(4)" ::: "memory");  // tile m+1 fully landed
    } else {
      asm volatile("s_waitcnt vmcnt(0)" ::: "memory");
    }
    __builtin_amdgcn_s_barrier();
    __builtin_amdgcn_sched_barrier(0);
    MFMA_Q(4, 0);                      // bv[0..3] still resident
    BAR_END();

    // ================= tile m+1 (buf1) =================
    READ_A(32768, 0);
    READ_B(32768, 0);
    if (more) stageA(0, 0, m + 2);     // buf0.A free after P3
    BAR_LGKM();
    MFMA_Q(0, 0);
    BAR_END();

    READ_B(32768, 1);
    if (more) stageA(0, 1, m + 2);
    BAR_LGKM();
    MFMA_Q(0, 2);
    BAR_END();

    READ_A(32768, 4096);
    if (more) stageB(1, 0, m + 3);     // buf1.B free after P6
    BAR_LGKM();
    MFMA_Q(4, 2);
    BAR_END();

    if (more) {
      stageB(1, 1, m + 3);
      asm volatile("s_waitcnt vmcnt(4)" ::: "memory");  // tile m+2 landed
    } else {
      asm volatile("s_waitcnt vmcnt(0)" ::: "memory");
    }
    __builtin_amdgcn_s_barrier();
    __builtin_amdgcn_sched_barrier(0);
    MFMA_Q(4, 0);
    BAR_END();
  }

  // ---------------- epilogue ----------------
  const int rowb = bm + wm * 128 + fq * 4;
  const int colb = bn + wn * 64 + fr;
#pragma unroll
  for (int nf = 0; nf < 4; ++nf) {
    const int colg = colb + nf * 16;
    const float bvs = (MODE == 4) ? 0.f : bias[colg];
#pragma unroll
    for (int mf = 0; mf < 8; ++mf) {
#pragma unroll
      for (int r = 0; r < 4; ++r) {
        const int rowg = rowb + mf * 16 + r;
        const size_t idx = (size_t)rowg * N + colg;
        float v = acc[mf][nf][r];
        if (MODE == 0) {
          outF[idx] = v + bvs + resid[idx];
        } else if (MODE == 2) {
          v += bvs;
          // gelu(x) ~= x * sigmoid(1.5957691(x + 0.044715 x^3)); maxerr ~1e-3
          float u = 1.5957691216f * (v + 0.044715f * v * v * v);
          v = v / (1.f + __expf(-u));
          outB[idx] = f2bf(v);
        } else {  // MODE 4
          float o;
          if (colg < 1024)
            o = (v >= 0.f) ? (v + 0.5f) : (1.f / (1.f + __expf(-v)));  // g(hidden)
          else
            o = 1.f / (1.f + __expf(v));                               // sigmoid(-gate)
          outB[idx] = f2bf(o);
        }
      }
    }
  }
}

// ---------------- minGRU linear-space chunked scan (pure FMA) ----------------
// hg layout: [T][2048], col<1024: ghid, col>=1024: a. h_t = a h_{t-1} + (1-a) ghid.
__global__ __launch_bounds__(256) void scan_p1(const ushort* __restrict__ hg,
                                               float* __restrict__ Ag,
                                               float* __restrict__ Bg) {
  int blk = blockIdx.x;
  int dt = blk & 3, ch = (blk >> 2) & 31, b = blk >> 7;
  int d = (dt << 8) + threadIdx.x;
  const ushort* p = hg + (size_t)(b * L_ + ch * CHL) * 2048 + d;
  float A = 1.f, Bv = 0.f;
  for (int s = 0; s < CHL; ++s) {
    float g = bf2f(p[0]), a = bf2f(p[1024]);
    p += 2048;
    A *= a;
    Bv = fmaf(a, Bv, (1.f - a) * g);
  }
  size_t o = (size_t)((b * NCH + ch) * D_) + d;
  Ag[o] = A; Bg[o] = Bv;
}

__global__ __launch_bounds__(256) void scan_p2(const float* __restrict__ Ag,
                                               const float* __restrict__ Bg,
                                               float* __restrict__ Pre) {
  int dt = blockIdx.x & 3, b = blockIdx.x >> 2;
  int d = (dt << 8) + threadIdx.x;
  float h = 0.f;
  for (int c = 0; c < NCH; ++c) {
    size_t i = (size_t)((b * NCH + c) * D_) + d;
    Pre[i] = h;
    h = fmaf(Ag[i], h, Bg[i]);
  }
}

__global__ __launch_bounds__(256) void scan_p3(const ushort* __restrict__ hg,
                                               const float* __restrict__ Pre,
                                               float* __restrict__ xio,
                                               float* __restrict__ nh) {
  int blk = blockIdx.x;
  int dt = blk & 3, ch = (blk >> 2) & 31, b = blk >> 7;
  int d = (dt << 8) + threadIdx.x;
  const ushort* p = hg + (size_t)(b * L_ + ch * CHL) * 2048 + d;
  float* q = xio + (size_t)(b * L_ + ch * CHL) * D_ + d;
  float h = Pre[(size_t)((b * NCH + ch) * D_) + d];
  for (int s = 0; s < CHL; ++s) {
    float g = bf2f(p[0]), a = bf2f(p[1024]);
    p += 2048;
    h = fmaf(a, h, (1.f - a) * g);
    *q = h + *q;
    q += D_;
  }
  if (ch == NCH - 1) nh[(b << 10) + d] = h;
}

// ---------------- launcher ----------------
extern "C" void kernel_launch(void* const* d_in, const int* in_sizes, int n_in,
                              void* d_out, int out_size, void* d_ws, size_t ws_size,
                              hipStream_t stream) {
  const float* x   = (const float*)d_in[0];
  const float* cdw = (const float*)d_in[1];
  const float* cdb = (const float*)d_in[2];
  const float* cpw = (const float*)d_in[3];
  const float* cpb = (const float*)d_in[4];
  const float* cng = (const float*)d_in[5];
  const float* gng = (const float*)d_in[6];
  const float* gw  = (const float*)d_in[7];
  const float* fng = (const float*)d_in[8];
  const float* fw1 = (const float*)d_in[9];
  const float* fb1 = (const float*)d_in[10];
  const float* fw2 = (const float*)d_in[11];
  const float* fb2 = (const float*)d_in[12];
  float* out = (float*)d_out;
  char* ws = (char*)d_ws;

  // workspace layout (bytes)
  ushort* wpw_b = (ushort*)(ws + 0);          //  2 MiB
  ushort* wgr_b = (ushort*)(ws + 2097152);    //  4 MiB
  ushort* wf1_b = (ushort*)(ws + 6291456);    //  8 MiB
  ushort* wf2_b = (ushort*)(ws + 14680064);   //  8 MiB
  float*  Ag    = (float*) (ws + 23134208);   // 512 KiB
  float*  Bg    = (float*) (ws + 23658496);   // 512 KiB
  float*  Pre   = (float*) (ws + 24182784);   // 512 KiB
  ushort* zbuf  = (ushort*)(ws + 24707072);   // 32 MiB (y / z1 / z2, reused)
  ushort* hg    = (ushort*)(ws + 58261504);   // 64 MiB bf16 [T][2048] (ghid | a)
  ushort* h1    = (ushort*)(ws + 58261504);   // 128 MiB bf16 [T][4096] (overlays hg)
  float*  nh    = out + (size_t)T_ * D_;      // next_hidden tail of d_out

  // all weights -> bf16 (one launch; 2883584 float4 units / 256 = 11264 blocks)
  cvt_all<<<dim3(11264), 256, 0, stream>>>(cpw, wpw_b, gw, wgr_b, fw1, wf1_b, fw2, wf2_b);

  // stage 1: fused rmsnorm + causal dwconv -> y (bf16); x1 = y@Wpw^T + b + x
  dwconv_k<<<dim3(T_ / 4), 256, 0, stream>>>(x, cdw, cdb, cng, zbuf);
  gemm256<0><<<dim3(4, 64), 512, 0, stream>>>(zbuf, wpw_b, cpb, x, out, nullptr, T_, 1024, 1024);

  // stage 2: z1 = rmsnorm(x1)*g; hg = gate-transform(z1 @ Wgru^T); scan; x2 = h + x1
  rms_scale<<<dim3(T_), 256, 0, stream>>>(out, gng, zbuf);
  gemm256<4><<<dim3(8, 64), 512, 0, stream>>>(zbuf, wgr_b, nullptr, nullptr, nullptr, hg, T_, 2048, 1024);
  scan_p1<<<dim3(512), 256, 0, stream>>>(hg, Ag, Bg);
  scan_p2<<<dim3(16), 256, 0, stream>>>(Ag, Bg, Pre);
  scan_p3<<<dim3(512), 256, 0, stream>>>(hg, Pre, out, nh);

  // stage 3: z2 = rmsnorm(x2)*g; h1 = gelu(z2@W1^T + b1); out = h1@W2^T + b2 + x2
  rms_scale<<<dim3(T_), 256, 0, stream>>>(out, fng, zbuf);
  gemm256<2><<<dim3(16, 64), 512, 0, stream>>>(zbuf, wf1_b, fb1, nullptr, nullptr, h1, T_, 4096, 1024);
  gemm256<0><<<dim3(4, 64), 512, 0, stream>>>(h1, wf2_b, fb2, out, out, nullptr, T_, 1024, 4096);
}